// Round 9
// baseline (3474.139 us; speedup 1.0000x reference)
//
#include <hip/hip_runtime.h>

// Sinkhorn EMD (ApproximatedEMDLoss), B=16, N=2048, D=3, eps=0.01, 50 iters.
//
// R7: spatial culling. Measured machine model (R5/R6 counters): wave64
// v_sqrt/v_exp each block VALU issue ~16 cyc (quarter-rate trans pipe);
// per pair = 7 VALU x2 + 2 trans x16 = 46 cyc -> all dense structures pin at
// ~24-26us/pass. Only lever: fewer pairs. K=2^(-144.27 d) terms with
// arg > dmin_row + 30 are < 2^-30 of the row max -> invisible in f32 sums.
//  - Morton-cell counting sort of both sets (block's 64 rows spatially compact)
//  - per-row dmin tracked in the 2 unavoidable dense passes
//  - chunk-level (32 cols) bbox cull + per-column wave-unanimous skip
// Weight chain identical to R6: s_j=sum_i K_ij; w0=1/s; p=Kw (u=kR/p);
// q=K^T u (next w = kR/q; v = kR*s/q). Loss = sum u K v C.

namespace {
constexpr int kB = 16;
constexpr int kN = 2048;
constexpr int NT = 512;                 // 8 waves/block
constexpr int WAVES = NT / 64;
constexpr int ROWS = 64;                // rows per block (one per lane)
constexpr int BPB = kN / ROWS;          // 32 blocks per batch
constexpr int GRID = kB * BPB;          // 512 blocks
constexpr int CH = 32;                  // columns per chunk
constexpr int NCHUNK = kN / CH;         // 64 chunks
constexpr float kR = 1.0f / (float)kN;
constexpr float kScale = 144.26950408889634f;  // 100 * log2(e)
constexpr float kMargin = 30.0f;        // scaled-arg drop margin (2^-30)

__device__ __forceinline__ float wmaxf(float v) {
#pragma unroll
  for (int m = 1; m < 64; m <<= 1) v = fmaxf(v, __shfl_xor(v, m));
  return v;
}
__device__ __forceinline__ float wminf(float v) {
#pragma unroll
  for (int m = 1; m < 64; m <<= 1) v = fminf(v, __shfl_xor(v, m));
  return v;
}
__device__ __forceinline__ int expand3(int v) {
  return (v & 1) | ((v & 2) << 2) | ((v & 4) << 4);
}
}  // namespace

// Counting sort by 512-cell Morton code; writes scaled packed float4.
// grid 32: blockIdx = b*2 + set (set0 = x/pc1 w=1, set1 = y/pc2 w=0).
__global__ __launch_bounds__(NT) void emd_sort(
    const float* __restrict__ pc1, const float* __restrict__ pc2,
    float4* __restrict__ px, float4* __restrict__ py) {
  __shared__ int h[512], e[512];
  const int b = blockIdx.x >> 1, set = blockIdx.x & 1;
  const float* src = set ? pc2 : pc1;
  float4* dst = (set ? py : px) + b * kN;
  const float winit = set ? 0.0f : 1.0f;
  const int tid = threadIdx.x;

  h[tid] = 0;
  __syncthreads();
  int cells[kN / NT];
#pragma unroll
  for (int k = 0; k < kN / NT; ++k) {
    int j = tid + k * NT;
    const float* p = src + (b * kN + j) * 3;
    int cx = min(7, max(0, (int)(p[0] * 8.0f)));
    int cy = min(7, max(0, (int)(p[1] * 8.0f)));
    int cz = min(7, max(0, (int)(p[2] * 8.0f)));
    int m = expand3(cx) | (expand3(cy) << 1) | (expand3(cz) << 2);
    cells[k] = m;
    atomicAdd(&h[m], 1);
  }
  __syncthreads();
  e[tid] = h[tid];
  __syncthreads();
  for (int off = 1; off < 512; off <<= 1) {
    int v = (tid >= off) ? e[tid - off] : 0;
    __syncthreads();
    e[tid] += v;
    __syncthreads();
  }
  h[tid] = e[tid] - h[tid];   // exclusive offset, reused as cursor
  __syncthreads();
#pragma unroll
  for (int k = 0; k < kN / NT; ++k) {
    int j = tid + k * NT;
    const float* p = src + (b * kN + j) * 3;
    int idx = atomicAdd(&h[cells[k]], 1);
    dst[idx] = make_float4(p[0] * kScale, p[1] * kScale, p[2] * kScale, winit);
  }
}

// Chunk bboxes: grid 32 (set*16+b), block 64 (thread = chunk).
__global__ __launch_bounds__(64) void emd_bbox(
    const float4* __restrict__ px, const float4* __restrict__ py,
    float4* __restrict__ bmin, float4* __restrict__ bmax) {
  const int set = blockIdx.x >> 4, b = blockIdx.x & 15;
  const float4* src = (set ? py : px) + b * kN + threadIdx.x * CH;
  float mnx = 3e38f, mny = 3e38f, mnz = 3e38f;
  float mxx = -3e38f, mxy = -3e38f, mxz = -3e38f;
  for (int k = 0; k < CH; ++k) {
    float4 p = src[k];
    mnx = fminf(mnx, p.x); mny = fminf(mny, p.y); mnz = fminf(mnz, p.z);
    mxx = fmaxf(mxx, p.x); mxy = fmaxf(mxy, p.y); mxz = fmaxf(mxz, p.z);
  }
  bmin[blockIdx.x * NCHUNK + threadIdx.x] = make_float4(mnx, mny, mnz, 0.f);
  bmax[blockIdx.x * NCHUNK + threadIdx.x] = make_float4(mxx, mxy, mxz, 0.f);
}

// One matvec pass. CULL: chunk bbox cull + per-column unanimous skip.
// TRACK: record per-row min distance (dense passes 0/1). STORE_S: write s.
// FOLD_S: epilogue rows.w = mult*s/sum (last q-pass), else mult/sum.
template <bool CULL, bool TRACK, bool STORE_S, bool FOLD_S>
__global__ __launch_bounds__(NT, 4) void emd_pass(
    float4* __restrict__ rows, const float4* __restrict__ cols,
    const float4* __restrict__ cbmin, const float4* __restrict__ cbmax,
    float* __restrict__ dminarg, float* __restrict__ s_arr, float mult) {
  __shared__ float partial[WAVES][ROWS];
  __shared__ float dpart[TRACK ? WAVES : 1][TRACK ? ROWS : 1];
  const int b = blockIdx.x >> 5;
  const int rowbase = (blockIdx.x & 31) * ROWS;
  const int lane = threadIdx.x & 63;
  const int wav = threadIdx.x >> 6;
  const int rowi = b * kN + rowbase + lane;

  const float4 r = rows[rowi];

  float cut2 = 0.f;
  unsigned long long mask = ~0ull;
  if (CULL) {
    float cut = wmaxf(dminarg[rowi]) + kMargin;
    cut2 = cut * cut;
    // group bbox over the 64 rows (every wave computes identically)
    float gminx = wminf(r.x), gmaxx = wmaxf(r.x);
    float gminy = wminf(r.y), gmaxy = wmaxf(r.y);
    float gminz = wminf(r.z), gmaxz = wmaxf(r.z);
    float4 bn = cbmin[b * NCHUNK + lane];
    float4 bx = cbmax[b * NCHUNK + lane];
    float dx = fmaxf(0.f, fmaxf(bn.x - gmaxx, gminx - bx.x));
    float dy = fmaxf(0.f, fmaxf(bn.y - gmaxy, gminy - bx.y));
    float dz = fmaxf(0.f, fmaxf(bn.z - gmaxz, gminz - bx.z));
    float d2c = fmaf(dx, dx, fmaf(dy, dy, dz * dz));
    mask = __ballot(d2c <= cut2);
  }

  float acc = 0.f;
  float d2m = 3.4e38f;
  int cnt = 0;
  const float4* cb = cols + b * kN;
  for (int c = 0; c < NCHUNK; ++c) {
    if (!((mask >> c) & 1ull)) continue;
    if ((cnt++ & (WAVES - 1)) != wav) continue;
    const float4* cp = cb + c * CH;
#pragma unroll 4
    for (int k = 0; k < CH; ++k) {
      float4 c4 = cp[k];
      float dx = r.x - c4.x, dy = r.y - c4.y, dz = r.z - c4.z;
      float d2 = fmaf(dx, dx, fmaf(dy, dy, dz * dz));
      if (TRACK) d2m = fminf(d2m, d2);
      if (CULL) {
        if (__all(d2 > cut2)) continue;     // whole wave beyond cutoff
      }
      float ds = __builtin_amdgcn_sqrtf(d2);
      acc = fmaf(__builtin_amdgcn_exp2f(-ds), c4.w, acc);
    }
  }
  partial[wav][lane] = acc;
  if (TRACK) dpart[wav][lane] = d2m;
  __syncthreads();
  if (wav == 0) {
    float sum = partial[0][lane];
#pragma unroll
    for (int w2 = 1; w2 < WAVES; ++w2) sum += partial[w2][lane];
    if (TRACK) {
      float dm = dpart[0][lane];
#pragma unroll
      for (int w2 = 1; w2 < WAVES; ++w2) dm = fminf(dm, dpart[w2][lane]);
      dminarg[rowi] = __builtin_amdgcn_sqrtf(dm);
    }
    if (STORE_S) s_arr[rowi] = sum;
    float wnew = FOLD_S ? (mult * s_arr[rowi] / sum) : (mult / sum);
    reinterpret_cast<float*>(rows + rowi)[3] = wnew;
  }
}

// loss = mean_b sum_ij u_i K_ij v_j C_ij; u = xrows.w, v = ycols.w (folded),
// K*C = e*ds/kScale in scaled units.
__global__ __launch_bounds__(NT, 4) void emd_loss(
    const float4* __restrict__ xrows, const float4* __restrict__ ycols,
    const float4* __restrict__ cbmin, const float4* __restrict__ cbmax,
    const float* __restrict__ dmx, float* __restrict__ out) {
  __shared__ float partial[WAVES][ROWS];
  const int b = blockIdx.x >> 5;
  const int rowbase = (blockIdx.x & 31) * ROWS;
  const int lane = threadIdx.x & 63;
  const int wav = threadIdx.x >> 6;
  const int rowi = b * kN + rowbase + lane;

  const float4 r = xrows[rowi];                  // .w = u_i
  float cut = wmaxf(dmx[rowi]) + kMargin;
  float cut2 = cut * cut;
  float gminx = wminf(r.x), gmaxx = wmaxf(r.x);
  float gminy = wminf(r.y), gmaxy = wmaxf(r.y);
  float gminz = wminf(r.z), gmaxz = wmaxf(r.z);
  float4 bn = cbmin[b * NCHUNK + lane];
  float4 bx = cbmax[b * NCHUNK + lane];
  float ddx = fmaxf(0.f, fmaxf(bn.x - gmaxx, gminx - bx.x));
  float ddy = fmaxf(0.f, fmaxf(bn.y - gmaxy, gminy - bx.y));
  float ddz = fmaxf(0.f, fmaxf(bn.z - gmaxz, gminz - bx.z));
  unsigned long long mask =
      __ballot(fmaf(ddx, ddx, fmaf(ddy, ddy, ddz * ddz)) <= cut2);

  float acc = 0.f;
  int cnt = 0;
  const float4* cbase = ycols + b * kN;
  for (int c = 0; c < NCHUNK; ++c) {
    if (!((mask >> c) & 1ull)) continue;
    if ((cnt++ & (WAVES - 1)) != wav) continue;
    const float4* cp = cbase + c * CH;
#pragma unroll 4
    for (int k = 0; k < CH; ++k) {
      float4 c4 = cp[k];
      float dx = r.x - c4.x, dy = r.y - c4.y, dz = r.z - c4.z;
      float d2 = fmaf(dx, dx, fmaf(dy, dy, dz * dz));
      if (__all(d2 > cut2)) continue;
      float ds = __builtin_amdgcn_sqrtf(d2);
      acc = fmaf(__builtin_amdgcn_exp2f(-ds) * ds, c4.w, acc);
    }
  }
  partial[wav][lane] = acc;
  __syncthreads();
  if (wav == 0) {
    float sum = partial[0][lane];
#pragma unroll
    for (int w2 = 1; w2 < WAVES; ++w2) sum += partial[w2][lane];
    float t = sum * r.w;
#pragma unroll
    for (int m = 1; m < 64; m <<= 1) t += __shfl_xor(t, m);
    if (lane == 0) atomicAdd(out, t * (1.0f / (kScale * (float)kB)));
  }
}

extern "C" void kernel_launch(void* const* d_in, const int* in_sizes, int n_in,
                              void* d_out, int out_size, void* d_ws, size_t ws_size,
                              hipStream_t stream) {
  const float* pc1 = (const float*)d_in[0];
  const float* pc2 = (const float*)d_in[1];
  float4* px = (float4*)d_ws;                  // [B*N] sorted scaled x + w
  float4* py = px + kB * kN;                   // [B*N] sorted scaled y + w
  float4* bmin = py + kB * kN;                 // [2*16*64] chunk bbox mins
  float4* bmax = bmin + 2 * kB * NCHUNK;       // [2*16*64] chunk bbox maxs
  float* s = (float*)(bmax + 2 * kB * NCHUNK); // [B*N] column sums of K
  float* dmx = s + kB * kN;                    // [B*N] x-row min dist (scaled)
  float* dmy = dmx + kB * kN;                  // [B*N] y-row min dist (scaled)
  const float4* cbX = bmin;                    // x-set chunk bboxes
  const float4* cbXmax = bmax;
  const float4* cbY = bmin + kB * NCHUNK;      // y-set chunk bboxes
  const float4* cbYmax = bmax + kB * NCHUNK;

  hipLaunchKernelGGL(emd_sort, dim3(2 * kB), dim3(NT), 0, stream,
                     pc1, pc2, px, py);
  hipLaunchKernelGGL(emd_bbox, dim3(2 * kB), dim3(64), 0, stream,
                     px, py, bmin, bmax);

  dim3 grid(GRID), block(NT);
  // s-pass (dense): rows=y vs cols=x; store s, track dmin_y; py.w = 1/s
  hipLaunchKernelGGL((emd_pass<false, true, true, false>), grid, block, 0,
                     stream, py, px, nullptr, nullptr, dmy, s, 1.0f);
  // p-pass 0 (dense): rows=x vs cols=y; track dmin_x; px.w = kR/p
  hipLaunchKernelGGL((emd_pass<false, true, false, false>), grid, block, 0,
                     stream, px, py, nullptr, nullptr, dmx, nullptr, kR);
  // q-pass 0 (culled): rows=y vs cols=x; py.w = kR/q
  hipLaunchKernelGGL((emd_pass<true, false, false, false>), grid, block, 0,
                     stream, py, px, cbX, cbXmax, dmy, nullptr, kR);
  for (int it = 1; it < 50; ++it) {
    hipLaunchKernelGGL((emd_pass<true, false, false, false>), grid, block, 0,
                       stream, px, py, cbY, cbYmax, dmx, nullptr, kR);
    if (it < 49) {
      hipLaunchKernelGGL((emd_pass<true, false, false, false>), grid, block, 0,
                         stream, py, px, cbX, cbXmax, dmy, nullptr, kR);
    } else {
      // last q-pass: fold s -> py.w = kR*s/q = v_j
      hipLaunchKernelGGL((emd_pass<true, false, false, true>), grid, block, 0,
                         stream, py, px, cbX, cbXmax, dmy, s, kR);
    }
  }
  hipMemsetAsync(d_out, 0, sizeof(float), stream);
  hipLaunchKernelGGL(emd_loss, grid, block, 0, stream,
                     px, py, cbY, cbYmax, dmx, (float*)d_out);
}

// Round 10
// 1229.012 us; speedup vs baseline: 2.8268x; 2.8268x over previous
//
#include <hip/hip_runtime.h>

// Sinkhorn EMD (ApproximatedEMDLoss), B=16, N=2048, D=3, eps=0.01, 50 iters.
//
// R10: static-sparsity materialization. R9 showed group-granular culling
// captures ~0% of the true sparsity (per-row ball r~0.25 => ~5% of columns).
// The pattern is geometry-only => build per-row u16 neighbor lists ONCE,
// then 100 sparse matvecs (one row per wave-iteration, coalesced list reads,
// LDS gather of packed {coords,w}). Dropped terms <= 2^-30 of row max;
// isolated-point u-blowup is cancelled by the row's enlarged cut.
// Chain: s_j=sum_i K_ij; w0=1/s; p=Kw (u=kR/p); q=K^T u (next w=kR/q;
// v=kR*s/q folded on last q). Loss = sum u K v C. ws guard -> dense fallback.

namespace {
constexpr int kB = 16;
constexpr int kN = 2048;
constexpr int NT = 512;                 // 8 waves/block
constexpr int WAVES = NT / 64;
constexpr int ROWS_D = 64;              // dense: rows/block (lane<->row)
constexpr int GRID_D = kB * (kN / ROWS_D);      // 512
constexpr int CH = 32;                  // dense col chunk
constexpr int NCHUNK = kN / CH;         // 64
constexpr int ROWS_S = 32;              // sparse/fill: rows/block
constexpr int RPW = ROWS_S / WAVES;     // 4 rows per wave
constexpr int GRID_S = kB * (kN / ROWS_S);      // 1024
constexpr int CAP = 384;                // list slots per row
constexpr float kR = 1.0f / (float)kN;
constexpr float kScale = 144.26950408889634f;   // 100 * log2(e)
constexpr float kMargin = 30.0f;        // 2^-30 drop margin (scaled arg)
constexpr unsigned short SENT = 0xFFFFu;

__device__ __forceinline__ int expand3(int v) {
  return (v & 1) | ((v & 2) << 2) | ((v & 4) << 4);
}
}  // namespace

// ---------- Morton counting sort; writes scaled packed float4 ----------
__global__ __launch_bounds__(NT) void emd_sort(
    const float* __restrict__ pc1, const float* __restrict__ pc2,
    float4* __restrict__ px, float4* __restrict__ py) {
  __shared__ int h[512], e[512];
  const int b = blockIdx.x >> 1, set = blockIdx.x & 1;
  const float* src = set ? pc2 : pc1;
  float4* dst = (set ? py : px) + b * kN;
  const float winit = set ? 0.0f : 1.0f;
  const int tid = threadIdx.x;
  h[tid] = 0;
  __syncthreads();
  int cells[kN / NT];
#pragma unroll
  for (int k = 0; k < kN / NT; ++k) {
    int j = tid + k * NT;
    const float* p = src + (b * kN + j) * 3;
    int cx = min(7, max(0, (int)(p[0] * 8.0f)));
    int cy = min(7, max(0, (int)(p[1] * 8.0f)));
    int cz = min(7, max(0, (int)(p[2] * 8.0f)));
    int m = expand3(cx) | (expand3(cy) << 1) | (expand3(cz) << 2);
    cells[k] = m;
    atomicAdd(&h[m], 1);
  }
  __syncthreads();
  e[tid] = h[tid];
  __syncthreads();
  for (int off = 1; off < 512; off <<= 1) {
    int v = (tid >= off) ? e[tid - off] : 0;
    __syncthreads();
    e[tid] += v;
    __syncthreads();
  }
  h[tid] = e[tid] - h[tid];
  __syncthreads();
#pragma unroll
  for (int k = 0; k < kN / NT; ++k) {
    int j = tid + k * NT;
    const float* p = src + (b * kN + j) * 3;
    int idx = atomicAdd(&h[cells[k]], 1);
    dst[idx] = make_float4(p[0] * kScale, p[1] * kScale, p[2] * kScale, winit);
  }
}

// ---------- dense pass (lane<->row, wave-strided chunks) ----------
template <bool TRACK, bool STORE_S, bool FOLD_S>
__global__ __launch_bounds__(NT, 4) void emd_dense(
    float4* __restrict__ rows, const float4* __restrict__ cols,
    float* __restrict__ dmin_out, float* __restrict__ s_arr, float mult) {
  __shared__ float partial[WAVES][ROWS_D];
  __shared__ float dpart[TRACK ? WAVES : 1][TRACK ? ROWS_D : 1];
  const int b = blockIdx.x >> 5;
  const int rowbase = (blockIdx.x & 31) * ROWS_D;
  const int lane = threadIdx.x & 63;
  const int wav = threadIdx.x >> 6;
  const int rowi = b * kN + rowbase + lane;
  const float4 r = rows[rowi];
  float acc = 0.f, d2m = 3.4e38f;
  const float4* cb = cols + b * kN;
  for (int c = wav; c < NCHUNK; c += WAVES) {
    const float4* cp = cb + c * CH;
#pragma unroll 8
    for (int k = 0; k < CH; ++k) {
      float4 c4 = cp[k];
      float dx = r.x - c4.x, dy = r.y - c4.y, dz = r.z - c4.z;
      float d2 = fmaf(dx, dx, fmaf(dy, dy, dz * dz));
      if (TRACK) d2m = fminf(d2m, d2);
      float ds = __builtin_amdgcn_sqrtf(d2);
      acc = fmaf(__builtin_amdgcn_exp2f(-ds), c4.w, acc);
    }
  }
  partial[wav][lane] = acc;
  if (TRACK) dpart[wav][lane] = d2m;
  __syncthreads();
  if (wav == 0) {
    float sum = partial[0][lane];
#pragma unroll
    for (int w2 = 1; w2 < WAVES; ++w2) sum += partial[w2][lane];
    if (TRACK) {
      float dm = dpart[0][lane];
#pragma unroll
      for (int w2 = 1; w2 < WAVES; ++w2) dm = fminf(dm, dpart[w2][lane]);
      dmin_out[rowi] = __builtin_amdgcn_sqrtf(dm);
    }
    if (STORE_S) s_arr[rowi] = sum;
    float wnew = FOLD_S ? (mult * s_arr[rowi] / sum) : (mult / sum);
    reinterpret_cast<float*>(rows + rowi)[3] = wnew;
  }
}

// ---------- dense loss (fallback; v folded into cols.w, u in rows.w) ----------
__global__ __launch_bounds__(NT, 4) void emd_loss_dense(
    const float4* __restrict__ xrows, const float4* __restrict__ ycols,
    float* __restrict__ out) {
  __shared__ float partial[WAVES][ROWS_D];
  const int b = blockIdx.x >> 5;
  const int rowbase = (blockIdx.x & 31) * ROWS_D;
  const int lane = threadIdx.x & 63;
  const int wav = threadIdx.x >> 6;
  const int rowi = b * kN + rowbase + lane;
  const float4 r = xrows[rowi];
  float acc = 0.f;
  const float4* cb = ycols + b * kN;
  for (int c = wav; c < NCHUNK; c += WAVES) {
    const float4* cp = cb + c * CH;
#pragma unroll 8
    for (int k = 0; k < CH; ++k) {
      float4 c4 = cp[k];
      float dx = r.x - c4.x, dy = r.y - c4.y, dz = r.z - c4.z;
      float d2 = fmaf(dx, dx, fmaf(dy, dy, dz * dz));
      float ds = __builtin_amdgcn_sqrtf(d2);
      acc = fmaf(__builtin_amdgcn_exp2f(-ds) * ds, c4.w, acc);
    }
  }
  partial[wav][lane] = acc;
  __syncthreads();
  if (wav == 0) {
    float sum = partial[0][lane];
#pragma unroll
    for (int w2 = 1; w2 < WAVES; ++w2) sum += partial[w2][lane];
    float t = sum * r.w;
#pragma unroll
    for (int m = 1; m < 64; m <<= 1) t += __shfl_xor(t, m);
    if (lane == 0) atomicAdd(out, t * (1.0f / (kScale * (float)kB)));
  }
}

// ---------- build per-row neighbor lists (one row per wave-iter) ----------
__global__ __launch_bounds__(NT) void emd_fill(
    const float4* __restrict__ rows, const float4* __restrict__ cols,
    const float* __restrict__ dmin, unsigned short* __restrict__ jlist,
    unsigned short* __restrict__ cnts) {
  __shared__ float4 cw[kN];
  const int b = blockIdx.x >> 6;
  const int rowbase = (blockIdx.x & 63) * ROWS_S;
  const int lane = threadIdx.x & 63;
  const int wav = threadIdx.x >> 6;
  for (int j = threadIdx.x; j < kN; j += NT) cw[j] = cols[b * kN + j];
  __syncthreads();
  for (int k = 0; k < RPW; ++k) {
    const int rowi = b * kN + rowbase + wav * RPW + k;
    const float4 r = rows[rowi];
    const float cut = dmin[rowi] + kMargin;
    const float cut2 = cut * cut;
    unsigned short* jl = jlist + (size_t)rowi * CAP;
    int base = 0;
    for (int it = 0; it < kN / 64; ++it) {
      int j = it * 64 + lane;
      float4 c4 = cw[j];
      float dx = r.x - c4.x, dy = r.y - c4.y, dz = r.z - c4.z;
      float d2 = fmaf(dx, dx, fmaf(dy, dy, dz * dz));
      bool pred = d2 <= cut2;
      unsigned long long m = __ballot(pred);
      int rank = __builtin_popcountll(m & ((1ull << lane) - 1ull));
      if (pred && (base + rank) < CAP) jl[base + rank] = (unsigned short)j;
      base += __builtin_popcountll(m);
    }
    if (lane == 0) cnts[rowi] = (base <= CAP) ? (unsigned short)base : SENT;
  }
}

// ---------- sparse pass / sparse loss ----------
template <bool FOLD_S, bool LOSS>
__global__ __launch_bounds__(NT) void emd_sparse(
    float4* __restrict__ rows, const float4* __restrict__ cols,
    const unsigned short* __restrict__ jlist,
    const unsigned short* __restrict__ cnts,
    const float* __restrict__ s_arr, float mult, float* __restrict__ out) {
  __shared__ float4 cw[kN];
  __shared__ float wred[WAVES];
  const int b = blockIdx.x >> 6;
  const int rowbase = (blockIdx.x & 63) * ROWS_S;
  const int lane = threadIdx.x & 63;
  const int wav = threadIdx.x >> 6;
  for (int j = threadIdx.x; j < kN; j += NT) cw[j] = cols[b * kN + j];
  __syncthreads();
  float t = 0.f;
  for (int k = 0; k < RPW; ++k) {
    const int rowi = b * kN + rowbase + wav * RPW + k;
    const float4 r = rows[rowi];
    const int cnt = cnts[rowi];
    float acc = 0.f;
    if (cnt == (int)SENT) {                    // overflow row: dense fallback
      for (int it = 0; it < kN / 64; ++it) {
        float4 c4 = cw[it * 64 + lane];
        float dx = r.x - c4.x, dy = r.y - c4.y, dz = r.z - c4.z;
        float d2 = fmaf(dx, dx, fmaf(dy, dy, dz * dz));
        float ds = __builtin_amdgcn_sqrtf(d2);
        float e = __builtin_amdgcn_exp2f(-ds);
        acc = fmaf(LOSS ? e * ds : e, c4.w, acc);
      }
    } else {
      const unsigned short* jl = jlist + (size_t)rowi * CAP;
      const int nit = (cnt + 63) >> 6;
      for (int it = 0; it < nit; ++it) {
        int idx = it * 64 + lane;
        bool valid = idx < cnt;
        int j = valid ? (int)jl[idx] : 0;
        float4 c4 = cw[j];
        float w = valid ? c4.w : 0.f;
        float dx = r.x - c4.x, dy = r.y - c4.y, dz = r.z - c4.z;
        float d2 = fmaf(dx, dx, fmaf(dy, dy, dz * dz));
        float ds = __builtin_amdgcn_sqrtf(d2);
        float e = __builtin_amdgcn_exp2f(-ds);
        acc = fmaf(LOSS ? e * ds : e, w, acc);
      }
    }
#pragma unroll
    for (int m = 1; m < 64; m <<= 1) acc += __shfl_xor(acc, m);
    if (LOSS) {
      t = fmaf(acc, r.w, t);                   // r.w = u_i
    } else if (lane == 0) {
      float wnew = FOLD_S ? (mult * s_arr[rowi] / acc) : (mult / acc);
      reinterpret_cast<float*>(rows + rowi)[3] = wnew;
    }
  }
  if (LOSS) {
    if (lane == 0) wred[wav] = t;
    __syncthreads();
    if (threadIdx.x == 0) {
      float bs = 0.f;
#pragma unroll
      for (int w2 = 0; w2 < WAVES; ++w2) bs += wred[w2];
      atomicAdd(out, bs * (1.0f / (kScale * (float)kB)));
    }
  }
}

extern "C" void kernel_launch(void* const* d_in, const int* in_sizes, int n_in,
                              void* d_out, int out_size, void* d_ws, size_t ws_size,
                              hipStream_t stream) {
  const float* pc1 = (const float*)d_in[0];
  const float* pc2 = (const float*)d_in[1];
  const size_t NR = (size_t)kB * kN;
  float4* px = (float4*)d_ws;                        // 512KB
  float4* py = px + NR;                              // 512KB
  float* s = (float*)(py + NR);                      // 128KB
  float* dmx = s + NR;                               // 128KB
  float* dmy = dmx + NR;                             // 128KB
  unsigned short* cnX = (unsigned short*)(dmy + NR); // 64KB
  unsigned short* cnY = cnX + NR;                    // 64KB
  unsigned short* jlX = cnY + NR;                    // 24MB
  unsigned short* jlY = jlX + NR * CAP;              // 24MB
  const size_t NEED = (char*)(jlY + NR * CAP) - (char*)d_ws;
  float* outp = (float*)d_out;

  hipMemsetAsync(d_out, 0, sizeof(float), stream);
  hipLaunchKernelGGL(emd_sort, dim3(2 * kB), dim3(NT), 0, stream,
                     pc1, pc2, px, py);
  dim3 gD(GRID_D), gS(GRID_S), blk(NT);
  // s-pass: rows=y, cols=x(w=1); store s, track dmy; py.w = 1/s
  hipLaunchKernelGGL((emd_dense<true, true, false>), gD, blk, 0, stream,
                     py, px, dmy, s, 1.0f);
  // p0: rows=x, cols=y; track dmx; px.w = kR/p = u
  hipLaunchKernelGGL((emd_dense<true, false, false>), gD, blk, 0, stream,
                     px, py, dmx, nullptr, kR);

  if (ws_size >= NEED) {
    hipLaunchKernelGGL(emd_fill, gS, blk, 0, stream, py, px, dmy, jlY, cnY);
    hipLaunchKernelGGL(emd_fill, gS, blk, 0, stream, px, py, dmx, jlX, cnX);
    // q0: py.w = kR/q
    hipLaunchKernelGGL((emd_sparse<false, false>), gS, blk, 0, stream,
                       py, px, jlY, cnY, nullptr, kR, nullptr);
    for (int it = 1; it < 50; ++it) {
      hipLaunchKernelGGL((emd_sparse<false, false>), gS, blk, 0, stream,
                         px, py, jlX, cnX, nullptr, kR, nullptr);
      if (it < 49) {
        hipLaunchKernelGGL((emd_sparse<false, false>), gS, blk, 0, stream,
                           py, px, jlY, cnY, nullptr, kR, nullptr);
      } else {  // last q folds s: py.w = kR*s/q = v_j
        hipLaunchKernelGGL((emd_sparse<true, false>), gS, blk, 0, stream,
                           py, px, jlY, cnY, s, kR, nullptr);
      }
    }
    hipLaunchKernelGGL((emd_sparse<false, true>), gS, blk, 0, stream,
                       px, py, jlX, cnX, nullptr, 0.0f, outp);
  } else {  // dense fallback (no list memory)
    hipLaunchKernelGGL((emd_dense<false, false, false>), gD, blk, 0, stream,
                       py, px, nullptr, nullptr, kR);
    for (int it = 1; it < 50; ++it) {
      hipLaunchKernelGGL((emd_dense<false, false, false>), gD, blk, 0, stream,
                         px, py, nullptr, nullptr, kR);
      if (it < 49) {
        hipLaunchKernelGGL((emd_dense<false, false, false>), gD, blk, 0, stream,
                           py, px, nullptr, nullptr, kR);
      } else {
        hipLaunchKernelGGL((emd_dense<false, false, true>), gD, blk, 0, stream,
                           py, px, nullptr, s, kR);
      }
    }
    hipLaunchKernelGGL(emd_loss_dense, gD, blk, 0, stream, px, py, outp);
  }
}